// Round 8
// baseline (276.235 us; speedup 1.0000x reference)
//
#include <hip/hip_runtime.h>
#include <hip/hip_bf16.h>
#include <stdint.h>

#define B_ 4
#define S_ 2048
#define H_ 1024

typedef __attribute__((ext_vector_type(4))) float f32x4;
typedef __attribute__((ext_vector_type(8))) short bf16x8;

#define AS1C(p) ((const __attribute__((address_space(1))) void*)(p))
#define AS3(p)  ((__attribute__((address_space(3))) void*)(p))
#define BAR()     __builtin_amdgcn_s_barrier()
#define SCHED0()  __builtin_amdgcn_sched_barrier(0)
#define WAITVM(n) asm volatile("s_waitcnt vmcnt(" #n ")" ::: "memory")

// ------- one-shot prep: convert X, Wq|Wk|Wv, pack biases, zero rsum -------
// grid-stride @2048 blocks (r4-proven: ~10 us faster than the 11k-block shape)
__global__ __launch_bounds__(256)
void prep_k(const float* __restrict__ X,
            const float* __restrict__ Wq, const float* __restrict__ Wk,
            const float* __restrict__ Wv,
            const float* __restrict__ bq, const float* __restrict__ bk,
            const float* __restrict__ bv,
            __hip_bfloat16* __restrict__ Xb, __hip_bfloat16* __restrict__ Wall,
            float* __restrict__ ball, float* __restrict__ rsum)
{
    const int NX = B_ * S_ * H_ / 4;   // float4 count of X
    const int NW = H_ * H_ / 4;        // float4 count of one W (2^18)
    const int TOT = NX + 3 * NW + 3 * H_ / 4 + B_ * S_ / 4;
    const int stride = gridDim.x * blockDim.x;
    for (int i = blockIdx.x * blockDim.x + threadIdx.x; i < TOT; i += stride) {
        if (i < NX + 3 * NW) {
            const float* src; uint64_t* dst; int li;
            if (i < NX) { src = X; dst = (uint64_t*)Xb; li = i; }
            else {
                int j = i - NX;
                int wsel = j / NW; li = j - wsel * NW;
                src = (wsel == 0) ? Wq : (wsel == 1) ? Wk : Wv;
                dst = (uint64_t*)Wall + (size_t)wsel * NW;
            }
            float4 v = ((const float4*)src)[li];
            union { __hip_bfloat16 h[4]; uint64_t u; } o;
            o.h[0] = __float2bfloat16(v.x);
            o.h[1] = __float2bfloat16(v.y);
            o.h[2] = __float2bfloat16(v.z);
            o.h[3] = __float2bfloat16(v.w);
            dst[li] = o.u;
        } else {
            int j = i - (NX + 3 * NW);
            if (j < 3 * H_ / 4) {                    // bias pack (float4)
                int bsel = j >> 8;
                int off  = j & 255;
                const float* src = (bsel == 0) ? bq : (bsel == 1) ? bk : bv;
                ((float4*)ball)[j] = ((const float4*)src)[off];
            } else {                                  // zero rsum (float4)
                int j2 = j - 3 * H_ / 4;
                ((float4*)rsum)[j2] = make_float4(0.f, 0.f, 0.f, 0.f);
            }
        }
    }
}

// =====================================================================
// r8: depth-3 ring GEMM — r7 with the staging-offset bug fixed.
//   BUG WAS: stage() used g*8192 element spacing; a g-block is 512thr x 8elem
//   = 4096 elements (64 rows x 64 cols). 8192 left A-rows 64..127 stale and
//   overflowed lA into lB (NaN). Correct spacing: g*4096 (matches the r3
//   2-phase kernel's proven geometry).
// C[M,N] = scale * (A[M,K] @ B[N,K]^T) [+ bias]
// Tile 256x128, BK=64, 8 waves (4M x 2N), wave tile 64x64 (4x4 frags).
// LDS: 3 stages x (256+128) x 64 x 2B = 144 KB -> 1 block/CU.
// Per iter t:
//   ds_read slot(t) frags (lgkm-gated by compiler) + 32 MFMA      [compute]
//   s_barrier                  <- all waves' reads of slot(t) consumed
//   stage(slot(t), tile t+3)   <- overwrite issue, 6 gloads/wave
//   sched_barrier(0)           <- pin loads BEFORE the counted wait
//   vmcnt(12)                  <- tiles t+2,t+3 (12 loads) may fly; t+1 LANDED
//   s_barrier                  <- per-wave guarantee made collective
// Hazard ledger (re-audited r8):
//   during compute of iter u (reading slot u%3), in-flight writes target
//   only slots (u+1)%3 and (u+2)%3 (disjoint); gate at u-1 guaranteed
//   tile u landed; WAR: a wave at barrier#1 has completed all ds_reads of
//   the slot (MFMA data-dependence forces lgkmcnt). Tail gates 12->6->0.
// Staging/fragment swizzle byte-identical to the r0-proven legacy kernel:
// phys chunk = logical ^ (row&7) both sides -> measured 0 bank conflicts.
// =====================================================================
template<bool OUT_BF16, bool HAS_BIAS, bool V_SPLIT, bool EXP_SUM, bool ROWDIV>
__global__ __launch_bounds__(512, 1)
void gemm3r(const __hip_bfloat16* __restrict__ A, int lda, long long aBatch,
            const __hip_bfloat16* __restrict__ B, int ldb, long long bBatch,
            const float* __restrict__ bias,
            void* __restrict__ Cout, int ldc, long long cBatch,
            __hip_bfloat16* __restrict__ vtrans, float* __restrict__ rsum,
            int K, float scale)
{
    __shared__ __hip_bfloat16 lA[3][256 * 64];
    __shared__ __hip_bfloat16 lB[3][128 * 64];

    const int t  = threadIdx.x;
    const int bz = blockIdx.z;
    A += (long long)bz * aBatch;
    B += (long long)bz * bBatch;
    const int bm = blockIdx.y * 256;
    const int bn = blockIdx.x * 128;

    const int wave = t >> 6;
    const int lane = t & 63;
    const int wm = (wave >> 1) * 64;      // 4 M-positions
    const int wn = (wave & 1) * 64;       // 2 N-positions
    const int lm = lane & 15;
    const int kq = lane >> 4;
    const int cro = lm & 7;

    f32x4 acc[4][4] = {};

    // staging: thread t -> row srow (0..63) (+g*64), swizzled 16B chunk
    const int srow = t >> 3;
    const int swz  = ((t & 7) ^ (srow & 7)) * 8;
    const __hip_bfloat16* gA = A + (long long)(bm + srow) * lda + swz;
    const __hip_bfloat16* gB = B + (long long)(bn + srow) * ldb + swz;

    auto stage = [&](int s, int k0) {
        __hip_bfloat16* dA = lA[s] + t * 8;
        __hip_bfloat16* dB = lB[s] + t * 8;
#pragma unroll
        for (int g = 0; g < 4; ++g)
            __builtin_amdgcn_global_load_lds(AS1C(gA + (long long)g * 64 * lda + k0),
                                             AS3(dA + g * 4096), 16, 0, 0);
#pragma unroll
        for (int g = 0; g < 2; ++g)
            __builtin_amdgcn_global_load_lds(AS1C(gB + (long long)g * 64 * ldb + k0),
                                             AS3(dB + g * 4096), 16, 0, 0);
    };

    // prologue: fill the ring (18 loads/wave); T0 must land -> vmcnt(12)
    stage(0, 0); stage(1, 64); stage(2, 128);
    SCHED0();
    WAITVM(12);
    SCHED0();
    BAR();
    SCHED0();

    const int nT = K >> 6;
    int sl = 0;
    for (int tt = 0; tt < nT; ++tt) {
        const __hip_bfloat16* cA = lA[sl] + (wm + lm) * 64;
        const __hip_bfloat16* cB = lB[sl] + (wn + lm) * 64;
#pragma unroll
        for (int ks = 0; ks < 2; ++ks) {
            const int ch = ((ks * 4 + kq) ^ cro) * 8;
            bf16x8 af[4], bfr[4];
#pragma unroll
            for (int i = 0; i < 4; ++i)
                af[i] = *(const bf16x8*)(cA + i * 16 * 64 + ch);
#pragma unroll
            for (int j = 0; j < 4; ++j)
                bfr[j] = *(const bf16x8*)(cB + j * 16 * 64 + ch);
#pragma unroll
            for (int i = 0; i < 4; ++i)
#pragma unroll
                for (int j = 0; j < 4; ++j)
                    acc[i][j] = __builtin_amdgcn_mfma_f32_16x16x32_bf16(
                        af[i], bfr[j], acc[i][j], 0, 0, 0);
        }
        if (tt + 1 < nT) {
            BAR();                          // all waves done reading slot sl
            SCHED0();
            if (tt + 3 < nT) stage(sl, (tt + 3) * 64);
            SCHED0();                       // pin loads before the counted wait
            if (tt + 3 < nT)      { WAITVM(12); }   // 2 newer tiles in flight
            else if (tt + 2 < nT) { WAITVM(6);  }   // 1 newer tile in flight
            else                  { WAITVM(0);  }   // drain: next is last tile
            SCHED0();
            BAR();                          // t+1 landed, collectively
            SCHED0();
            sl = (sl == 2) ? 0 : sl + 1;
        }
    }

    // ---------------- epilogue: C/D layout col = lane&15, row = kq*4 + reg ----
    const bool vmode = V_SPLIT && (bn >= 2 * H_);
    const int r0q = kq * 4;

    if (EXP_SUM) {
#pragma unroll
        for (int i = 0; i < 4; ++i) {
            const int rowb = bm + wm + i * 16 + r0q;
            float ps[4] = {0.f, 0.f, 0.f, 0.f};
#pragma unroll
            for (int j = 0; j < 4; ++j) {
                const int col = bn + wn + j * 16 + lm;
#pragma unroll
                for (int r = 0; r < 4; ++r) {
                    float e = __expf(acc[i][j][r] * scale);
                    ps[r] += e;
                    ((__hip_bfloat16*)Cout)[(long long)bz * cBatch +
                        (long long)(rowb + r) * ldc + col] = __float2bfloat16(e);
                }
            }
#pragma unroll
            for (int r = 0; r < 4; ++r) {
#pragma unroll
                for (int m = 1; m < 16; m <<= 1)
                    ps[r] += __shfl_xor(ps[r], m);
            }
            if (lm == 0) {
#pragma unroll
                for (int r = 0; r < 4; ++r)
                    atomicAdd(rsum + bz * S_ + rowb + r, ps[r]);
            }
        }
        return;
    }

#pragma unroll
    for (int i = 0; i < 4; ++i) {
        const int rowb = bm + wm + i * 16 + r0q;
        float inv[4];
        if (ROWDIV) {
            float4 rs = *(const float4*)(rsum + bz * S_ + rowb);
            inv[0] = 1.0f / rs.x; inv[1] = 1.0f / rs.y;
            inv[2] = 1.0f / rs.z; inv[3] = 1.0f / rs.w;
        }
#pragma unroll
        for (int j = 0; j < 4; ++j) {
            const int col = bn + wn + j * 16 + lm;
            float bvv = 0.0f;
            if (HAS_BIAS) bvv = bias[col];
            if (!vmode) {
#pragma unroll
                for (int r = 0; r < 4; ++r) {
                    float val = ROWDIV ? acc[i][j][r] * inv[r]
                                       : acc[i][j][r] * scale + bvv;
                    long long idx = (long long)bz * cBatch + (long long)(rowb + r) * ldc + col;
                    if (OUT_BF16) ((__hip_bfloat16*)Cout)[idx] = __float2bfloat16(val);
                    else          ((float*)Cout)[idx] = val;
                }
            } else {
                // vtrans[b][e][s]: b = rowb>>11, s = rowb&2047 (+r contiguous), e = col-2048
                const long long ebase = (long long)((rowb >> 11) * H_ + col - 2 * H_) * S_;
                union { ushort4 u; __hip_bfloat16 h[4]; } o;
#pragma unroll
                for (int r = 0; r < 4; ++r)
                    o.h[r] = __float2bfloat16(acc[i][j][r] + bvv);
                *(ushort4*)(vtrans + ebase + (rowb & 2047)) = o.u;
            }
        }
    }
}

// ---------------- launcher ----------------
extern "C" void kernel_launch(void* const* d_in, const int* in_sizes, int n_in,
                              void* d_out, int out_size, void* d_ws, size_t ws_size,
                              hipStream_t stream)
{
    const float* X  = (const float*)d_in[0];
    const float* Wq = (const float*)d_in[1];
    const float* bq = (const float*)d_in[2];
    const float* Wk = (const float*)d_in[3];
    const float* bk = (const float*)d_in[4];
    const float* Wv = (const float*)d_in[5];
    const float* bv = (const float*)d_in[6];
    float* out = (float*)d_out;

    char* w = (char*)d_ws;
    const size_t MB = 1ull << 20;
    // Layout (~80 MB):
    //   [0,16)   Xb          (dead after QKV gemm)
    //   [16,22)  Wall bf16 [3072,1024]   (dead after QKV gemm)
    //   [22,23)  ball fp32 [3072]        (dead after QKV gemm)
    //   [0,32)   sc  exp-scores bf16 [B,S,S]   (overlays dead Xb/Wall/ball)
    //   [32,64)  qk  bf16 [8192,2048]  (Q cols 0..1023, K cols 1024..2047)
    //   [64,80)  vtb bf16 [B,H,S]  (written transposed by QKV epilogue)
    //   [80MB, +32KB) rsum fp32 [B*S]
    __hip_bfloat16* Xb   = (__hip_bfloat16*)(w + 0);
    __hip_bfloat16* Wall = (__hip_bfloat16*)(w + 16 * MB);
    float*          ball = (float*)        (w + 22 * MB);
    __hip_bfloat16* sc   = (__hip_bfloat16*)(w + 0);
    __hip_bfloat16* qk   = (__hip_bfloat16*)(w + 32 * MB);
    __hip_bfloat16* vtb  = (__hip_bfloat16*)(w + 64 * MB);
    float*          rsum = (float*)        (w + 80 * MB);

    // 1. prep (X/W convert + bias pack + rsum zero) — grid-stride @2048 blocks
    prep_k<<<2048, 256, 0, stream>>>(X, Wq, Wk, Wv, bq, bk, bv,
                                     Xb, Wall, ball, rsum);

    // 2. fused QKV projection: depth-3 ring, 24x32 = 768 blocks = 3 rounds @1/CU
    dim3 g1(3 * H_ / 128, (B_ * S_) / 256, 1);
    gemm3r<true, true, true, false, false><<<g1, 512, 0, stream>>>(
        Xb, H_, 0, Wall, H_, 0, ball, qk, 2 * H_, 0, vtb, nullptr, H_, 1.0f);

    // 3. exp-scores: 16x8x4 = 512 blocks = 2 rounds @1/CU
    dim3 g2(S_ / 128, S_ / 256, B_);
    gemm3r<true, false, false, true, false><<<g2, 512, 0, stream>>>(
        qk,      2 * H_, (long long)S_ * 2 * H_,
        qk + H_, 2 * H_, (long long)S_ * 2 * H_,
        nullptr, sc, S_, (long long)S_ * S_, nullptr, rsum, H_, 0.03125f);

    // 4. out[b] = (exp-scores[b] @ vtb[b]^T) / rsum: 8x8x4 = 256 blocks = 1 round
    dim3 g3(H_ / 128, S_ / 256, B_);
    gemm3r<false, false, false, false, true><<<g3, 512, 0, stream>>>(
        sc,  S_, (long long)S_ * S_,
        vtb, S_, (long long)H_ * S_,
        nullptr, out, H_, (long long)S_ * H_, nullptr, rsum, S_, 1.0f);
}

// Round 9
// 267.132 us; speedup vs baseline: 1.0341x; 1.0341x over previous
//
#include <hip/hip_runtime.h>
#include <hip/hip_bf16.h>
#include <stdint.h>

#define B_ 4
#define S_ 2048
#define H_ 1024

typedef __attribute__((ext_vector_type(4))) float f32x4;
typedef __attribute__((ext_vector_type(8))) short bf16x8;

#define AS1C(p) ((const __attribute__((address_space(1))) void*)(p))
#define AS3(p)  ((__attribute__((address_space(3))) void*)(p))
#define BAR()     __builtin_amdgcn_s_barrier()
#define SCHED0()  __builtin_amdgcn_sched_barrier(0)
#define WAITVM(n) asm volatile("s_waitcnt vmcnt(" #n ")" ::: "memory")

// ------- one-shot prep: convert X, Wq|Wk|Wv, pack biases, zero rsum -------
__global__ __launch_bounds__(256)
void prep_k(const float* __restrict__ X,
            const float* __restrict__ Wq, const float* __restrict__ Wk,
            const float* __restrict__ Wv,
            const float* __restrict__ bq, const float* __restrict__ bk,
            const float* __restrict__ bv,
            __hip_bfloat16* __restrict__ Xb, __hip_bfloat16* __restrict__ Wall,
            float* __restrict__ ball, float* __restrict__ rsum)
{
    const int NX = B_ * S_ * H_ / 4;
    const int NW = H_ * H_ / 4;
    const int TOT = NX + 3 * NW + 3 * H_ / 4 + B_ * S_ / 4;
    const int stride = gridDim.x * blockDim.x;
    for (int i = blockIdx.x * blockDim.x + threadIdx.x; i < TOT; i += stride) {
        if (i < NX + 3 * NW) {
            const float* src; uint64_t* dst; int li;
            if (i < NX) { src = X; dst = (uint64_t*)Xb; li = i; }
            else {
                int j = i - NX;
                int wsel = j / NW; li = j - wsel * NW;
                src = (wsel == 0) ? Wq : (wsel == 1) ? Wk : Wv;
                dst = (uint64_t*)Wall + (size_t)wsel * NW;
            }
            float4 v = ((const float4*)src)[li];
            union { __hip_bfloat16 h[4]; uint64_t u; } o;
            o.h[0] = __float2bfloat16(v.x);
            o.h[1] = __float2bfloat16(v.y);
            o.h[2] = __float2bfloat16(v.z);
            o.h[3] = __float2bfloat16(v.w);
            dst[li] = o.u;
        } else {
            int j = i - (NX + 3 * NW);
            if (j < 3 * H_ / 4) {
                int bsel = j >> 8;
                int off  = j & 255;
                const float* src = (bsel == 0) ? bq : (bsel == 1) ? bk : bv;
                ((float4*)ball)[j] = ((const float4*)src)[off];
            } else {
                int j2 = j - 3 * H_ / 4;
                ((float4*)rsum)[j2] = make_float4(0.f, 0.f, 0.f, 0.f);
            }
        }
    }
}

// =====================================================================
// r9: faithful m201-style 8-phase 256x256 GEMM (T2+T3+T4+T5).
// C[M,N] = scale * (A[M,K] @ B[N,K]^T)
// 8 waves; wave C = 128x64 split ACROSS staging halves: rows = 64 in
// A-half0 + 64 in A-half1 (wm2=(wave>>2)*64), cols = 32 in B-half0 + 32
// in B-half1 (wn2=(wave&3)*32). Quadrant (Mh,Nh) therefore reads exactly
// one staging half of each operand -> per-phase stage/consume is legal.
// LDS: lA[2dbuf][2half][128x64] + lB[...] = 128 KB, 1 block/CU.
// Per ktile kt (dbuf d=kt&1), 4 phases:
//  q0: ldA(d,0)+ldB(d,0) | stage B0,B1(kt+1)->d^1 | bar | mm(0,0) | bar
//  q1: ldB(d,1)          | stage A0(kt+2)->d      | bar | mm(0,1) | bar
//  q2: ldA(d,1)+ldB(d,0) |                        | bar | mm(1,0) | bar
//  q3: ldB(d,1)          | stage A1(kt+2)->d      | bar | mm(1,1) |
//      vmcnt(4) [tail: (0)] | bar
// Hazard ledger:
//  WAR: each stage hits a slot whose last ds_read was lgkm-forced before
//    the previous barrier: A0 read q0 -> staged q1; A1 read q2 -> q3;
//    B(kt+1) slots (=kt-1's) last read q2/q3(kt-1) -> staged q0(kt). OK.
//  RAW: gate at end-q3(kt) with vmcnt(4) leaves only A0,A1(kt+2) in
//    flight -> all of kt+1 landed (B(kt+1)@q0 is older). Landing windows
//    4-7 phases. Tail: kt+2>=nkt -> vmcnt(0) drains B(kt+1).
//  Prologue: stage kt0 full + A0,A1(kt1) (12 loads), vmcnt(4) == steady.
// Swizzle: legacy-proven chunk XOR (phys = logical ^ (row&7), both sides).
// =====================================================================
template<bool EXP_SUM, bool ROWDIV, bool OUT_BF16>
__global__ __launch_bounds__(512, 1)
void gemm8p(const __hip_bfloat16* __restrict__ A, int lda, long long aBatch,
            const __hip_bfloat16* __restrict__ B, int ldb, long long bBatch,
            void* __restrict__ Cout, int ldc, long long cBatch,
            float* __restrict__ rsum, int K, float scale)
{
    __shared__ __hip_bfloat16 lA[2][2][128 * 64];
    __shared__ __hip_bfloat16 lB[2][2][128 * 64];

    const int t  = threadIdx.x;
    const int bz = blockIdx.z;
    A += (long long)bz * aBatch;
    B += (long long)bz * bBatch;
    const int bm = blockIdx.y * 256;
    const int bn = blockIdx.x * 256;

    const int wave = t >> 6, lane = t & 63;
    const int wm2 = (wave >> 2) * 64;     // M base within each A-half
    const int wn2 = (wave & 3) * 32;      // N base within each B-half
    const int lm = lane & 15, kq = lane >> 4;
    const int cro = lm & 7;

    f32x4 acc[8][4] = {};                 // [Mh*4+fi][Nh*2+nj]

    // staging: thread t -> row t>>3 (0..63) within an event, chunk t&7,
    // source pre-swizzled by row&7 (involution matches read side)
    const int srow = t >> 3;
    const int sch  = (t & 7) ^ (srow & 7);
    const __hip_bfloat16* gA = A + (long long)(bm + srow) * lda + sch * 8;
    const __hip_bfloat16* gB = B + (long long)(bn + srow) * ldb + sch * 8;

    auto stA = [&](int kt, int h) {       // 2 loads: rows h*128+{0,64}+srow
        const __hip_bfloat16* s = gA + (long long)(h * 128) * lda + kt * 64;
        __hip_bfloat16* d = &lA[kt & 1][h][t * 8];
        __builtin_amdgcn_global_load_lds(AS1C(s), AS3(d), 16, 0, 0);
        __builtin_amdgcn_global_load_lds(AS1C(s + (long long)64 * lda), AS3(d + 4096), 16, 0, 0);
    };
    auto stB = [&](int kt, int h) {
        const __hip_bfloat16* s = gB + (long long)(h * 128) * ldb + kt * 64;
        __hip_bfloat16* d = &lB[kt & 1][h][t * 8];
        __builtin_amdgcn_global_load_lds(AS1C(s), AS3(d), 16, 0, 0);
        __builtin_amdgcn_global_load_lds(AS1C(s + (long long)64 * ldb), AS3(d + 4096), 16, 0, 0);
    };

    bf16x8 af[2][4], bfr[2][2];
    auto ldA = [&](int d, int h) {
#pragma unroll
        for (int ks = 0; ks < 2; ++ks)
#pragma unroll
            for (int fi = 0; fi < 4; ++fi)
                af[ks][fi] = *(const bf16x8*)&lA[d][h][(wm2 + fi * 16 + lm) * 64 +
                                                       (((ks * 4 + kq) ^ cro) * 8)];
    };
    auto ldB = [&](int d, int h) {
#pragma unroll
        for (int ks = 0; ks < 2; ++ks)
#pragma unroll
            for (int nj = 0; nj < 2; ++nj)
                bfr[ks][nj] = *(const bf16x8*)&lB[d][h][(wn2 + nj * 16 + lm) * 64 +
                                                        (((ks * 4 + kq) ^ cro) * 8)];
    };
    auto mm = [&](int Mh, int Nh) {
        __builtin_amdgcn_s_setprio(1);
#pragma unroll
        for (int ks = 0; ks < 2; ++ks)
#pragma unroll
            for (int fi = 0; fi < 4; ++fi)
#pragma unroll
                for (int nj = 0; nj < 2; ++nj)
                    acc[Mh * 4 + fi][Nh * 2 + nj] = __builtin_amdgcn_mfma_f32_16x16x32_bf16(
                        af[ks][fi], bfr[ks][nj], acc[Mh * 4 + fi][Nh * 2 + nj], 0, 0, 0);
        __builtin_amdgcn_s_setprio(0);
    };

    const int nkt = K >> 6;
    // prologue
    stA(0, 0); stA(0, 1); stB(0, 0); stB(0, 1);
    stA(1, 0); stA(1, 1);
    SCHED0(); WAITVM(4); SCHED0(); BAR(); SCHED0();

    for (int kt = 0; kt < nkt; ++kt) {
        const int d = kt & 1;
        // ---- q0 ----
        ldA(d, 0); ldB(d, 0);
        if (kt + 1 < nkt) { stB(kt + 1, 0); stB(kt + 1, 1); }
        BAR(); SCHED0();
        mm(0, 0);
        BAR(); SCHED0();
        // ---- q1 ----
        ldB(d, 1);
        if (kt + 2 < nkt) stA(kt + 2, 0);
        BAR(); SCHED0();
        mm(0, 1);
        BAR(); SCHED0();
        // ---- q2 ----
        ldA(d, 1); ldB(d, 0);
        BAR(); SCHED0();
        mm(1, 0);
        BAR(); SCHED0();
        // ---- q3 ----
        ldB(d, 1);
        if (kt + 2 < nkt) stA(kt + 2, 1);
        BAR(); SCHED0();
        mm(1, 1);
        if (kt + 1 < nkt) {
            if (kt + 2 < nkt) { WAITVM(4); } else { WAITVM(0); }
        }
        SCHED0();
        BAR(); SCHED0();
    }

    // ---------------- epilogue: C/D layout col = lane&15, row = kq*4 + reg ----
    if (EXP_SUM) {
#pragma unroll
        for (int Mh = 0; Mh < 2; ++Mh)
#pragma unroll
        for (int fi = 0; fi < 4; ++fi) {
            const int rowb = bm + Mh * 128 + wm2 + fi * 16 + kq * 4;
            float ps[4] = {0.f, 0.f, 0.f, 0.f};
#pragma unroll
            for (int Nh = 0; Nh < 2; ++Nh)
#pragma unroll
            for (int nj = 0; nj < 2; ++nj) {
                const int col = bn + Nh * 128 + wn2 + nj * 16 + lm;
#pragma unroll
                for (int r = 0; r < 4; ++r) {
                    float e = __expf(acc[Mh * 4 + fi][Nh * 2 + nj][r] * scale);
                    ps[r] += e;
                    ((__hip_bfloat16*)Cout)[(long long)bz * cBatch +
                        (long long)(rowb + r) * ldc + col] = __float2bfloat16(e);
                }
            }
#pragma unroll
            for (int r = 0; r < 4; ++r) {
#pragma unroll
                for (int m = 1; m < 16; m <<= 1)
                    ps[r] += __shfl_xor(ps[r], m);
            }
            if (lm == 0) {
#pragma unroll
                for (int r = 0; r < 4; ++r)
                    atomicAdd(rsum + bz * S_ + rowb + r, ps[r]);
            }
        }
        return;
    }

#pragma unroll
    for (int Mh = 0; Mh < 2; ++Mh)
#pragma unroll
    for (int fi = 0; fi < 4; ++fi) {
        const int rowb = bm + Mh * 128 + wm2 + fi * 16 + kq * 4;
        float inv[4];
        if (ROWDIV) {
            float4 rs = *(const float4*)(rsum + bz * S_ + rowb);
            inv[0] = 1.0f / rs.x; inv[1] = 1.0f / rs.y;
            inv[2] = 1.0f / rs.z; inv[3] = 1.0f / rs.w;
        }
#pragma unroll
        for (int Nh = 0; Nh < 2; ++Nh)
#pragma unroll
        for (int nj = 0; nj < 2; ++nj) {
            const int col = bn + Nh * 128 + wn2 + nj * 16 + lm;
#pragma unroll
            for (int r = 0; r < 4; ++r) {
                float val = ROWDIV ? acc[Mh * 4 + fi][Nh * 2 + nj][r] * inv[r]
                                   : acc[Mh * 4 + fi][Nh * 2 + nj][r] * scale;
                long long idx = (long long)bz * cBatch + (long long)(rowb + r) * ldc + col;
                if (OUT_BF16) ((__hip_bfloat16*)Cout)[idx] = __float2bfloat16(val);
                else          ((float*)Cout)[idx] = val;
            }
        }
    }
}

// ------- legacy 128-tile B-transposed GEMM (QKV pass — r0-proven) -------
template<int BN, int MINW, bool OUT_BF16, bool HAS_BIAS, bool V_SPLIT, bool EXP_SUM, bool ROWDIV>
__global__ __launch_bounds__(256, MINW)
void gemm_bt(const __hip_bfloat16* __restrict__ A, int lda, long long aBatch,
             const __hip_bfloat16* __restrict__ B, int ldb, long long bBatch,
             const float* __restrict__ bias,
             void* __restrict__ Cout, int ldc, long long cBatch,
             __hip_bfloat16* __restrict__ vtrans, float* __restrict__ rsum,
             int M, int N, int K, float scale)
{
    constexpr int FJ = BN / 32;
    constexpr int SN = BN / 32;
    __shared__ __hip_bfloat16 lA[128 * 64];
    __shared__ __hip_bfloat16 lB[BN * 64];

    const int t  = threadIdx.x;
    const int bz = blockIdx.z;
    A += (long long)bz * aBatch;
    B += (long long)bz * bBatch;
    const int bm = blockIdx.y * 128;
    const int bn = blockIdx.x * BN;

    const int wave = t >> 6;
    const int lane = t & 63;
    const int wm = (wave & 1) * 64;
    const int wn = (wave >> 1) * (BN / 2);
    const int lm = lane & 15;
    const int kq = lane >> 4;
    const int cro = lm & 7;

    f32x4 acc[4][FJ] = {};

    const int srow = t >> 3;
    const int swz  = ((t & 7) ^ ((t >> 3) & 7)) * 8;
    const __hip_bfloat16* gA = A + (long long)(bm + srow) * lda + swz;
    const __hip_bfloat16* gB = B + (long long)(bn + srow) * ldb + swz;
    __hip_bfloat16* sA = lA + t * 8;
    __hip_bfloat16* sB = lB + t * 8;

    for (int k0 = 0; k0 < K; k0 += 64) {
        __syncthreads();
#pragma unroll
        for (int s = 0; s < 4; ++s)
            __builtin_amdgcn_global_load_lds(AS1C(gA + (long long)s * 32 * lda + k0),
                                             AS3(sA + s * 2048), 16, 0, 0);
#pragma unroll
        for (int s = 0; s < SN; ++s)
            __builtin_amdgcn_global_load_lds(AS1C(gB + (long long)s * 32 * ldb + k0),
                                             AS3(sB + s * 2048), 16, 0, 0);
        __syncthreads();

#pragma unroll
        for (int ks = 0; ks < 2; ++ks) {
            bf16x8 af[4], bfr[FJ];
            const int ch = ((ks * 4 + kq) ^ cro) * 8;
#pragma unroll
            for (int i = 0; i < 4; ++i)
                af[i] = *(const bf16x8*)(lA + (wm + i * 16 + lm) * 64 + ch);
#pragma unroll
            for (int j = 0; j < FJ; ++j)
                bfr[j] = *(const bf16x8*)(lB + (wn + j * 16 + lm) * 64 + ch);
#pragma unroll
            for (int i = 0; i < 4; ++i)
#pragma unroll
                for (int j = 0; j < FJ; ++j)
                    acc[i][j] = __builtin_amdgcn_mfma_f32_16x16x32_bf16(af[i], bfr[j], acc[i][j], 0, 0, 0);
        }
    }

    const bool vmode = V_SPLIT && (bn >= 2 * H_);
    const int r0q = kq * 4;

    if (EXP_SUM) {
#pragma unroll
        for (int i = 0; i < 4; ++i) {
            const int rowb = bm + wm + i * 16 + r0q;
            float ps[4] = {0.f, 0.f, 0.f, 0.f};
#pragma unroll
            for (int j = 0; j < FJ; ++j) {
                const int col = bn + wn + j * 16 + lm;
#pragma unroll
                for (int r = 0; r < 4; ++r) {
                    float e = __expf(acc[i][j][r] * scale);
                    ps[r] += e;
                    ((__hip_bfloat16*)Cout)[(long long)bz * cBatch +
                        (long long)(rowb + r) * ldc + col] = __float2bfloat16(e);
                }
            }
#pragma unroll
            for (int r = 0; r < 4; ++r) {
#pragma unroll
                for (int m = 1; m < 16; m <<= 1)
                    ps[r] += __shfl_xor(ps[r], m);
            }
            if (lm == 0) {
#pragma unroll
                for (int r = 0; r < 4; ++r)
                    atomicAdd(rsum + bz * S_ + rowb + r, ps[r]);
            }
        }
        return;
    }

#pragma unroll
    for (int i = 0; i < 4; ++i) {
        const int rowb = bm + wm + i * 16 + r0q;
        float inv[4];
        if (ROWDIV) {
            float4 rs = *(const float4*)(rsum + bz * S_ + rowb);
            inv[0] = 1.0f / rs.x; inv[1] = 1.0f / rs.y;
            inv[2] = 1.0f / rs.z; inv[3] = 1.0f / rs.w;
        }
#pragma unroll
        for (int j = 0; j < FJ; ++j) {
            const int col = bn + wn + j * 16 + lm;
            float bvv = 0.0f;
            if (HAS_BIAS) bvv = bias[col];
            if (!vmode) {
#pragma unroll
                for (int r = 0; r < 4; ++r) {
                    float val = ROWDIV ? acc[i][j][r] * inv[r]
                                       : acc[i][j][r] * scale + bvv;
                    long long idx = (long long)bz * cBatch + (long long)(rowb + r) * ldc + col;
                    if (OUT_BF16) ((__hip_bfloat16*)Cout)[idx] = __float2bfloat16(val);
                    else          ((float*)Cout)[idx] = val;
                }
            } else {
                // vtrans[b][e][s]: b = rowb>>11, s = rowb&2047 (+r contiguous), e = col-2048
                const long long ebase = (long long)((rowb >> 11) * H_ + col - 2 * H_) * S_;
                union { ushort4 u; __hip_bfloat16 h[4]; } o;
#pragma unroll
                for (int r = 0; r < 4; ++r)
                    o.h[r] = __float2bfloat16(acc[i][j][r] + bvv);
                *(ushort4*)(vtrans + ebase + (rowb & 2047)) = o.u;
            }
        }
    }
}

// ---------------- launcher ----------------
extern "C" void kernel_launch(void* const* d_in, const int* in_sizes, int n_in,
                              void* d_out, int out_size, void* d_ws, size_t ws_size,
                              hipStream_t stream)
{
    const float* X  = (const float*)d_in[0];
    const float* Wq = (const float*)d_in[1];
    const float* bq = (const float*)d_in[2];
    const float* Wk = (const float*)d_in[3];
    const float* bk = (const float*)d_in[4];
    const float* Wv = (const float*)d_in[5];
    const float* bv = (const float*)d_in[6];
    float* out = (float*)d_out;

    char* w = (char*)d_ws;
    const size_t MB = 1ull << 20;
    __hip_bfloat16* Xb   = (__hip_bfloat16*)(w + 0);
    __hip_bfloat16* Wall = (__hip_bfloat16*)(w + 16 * MB);
    float*          ball = (float*)        (w + 22 * MB);
    __hip_bfloat16* sc   = (__hip_bfloat16*)(w + 0);
    __hip_bfloat16* qk   = (__hip_bfloat16*)(w + 32 * MB);
    __hip_bfloat16* vtb  = (__hip_bfloat16*)(w + 64 * MB);
    float*          rsum = (float*)        (w + 80 * MB);

    // 1. prep — grid-stride @2048 blocks (r4-proven)
    prep_k<<<2048, 256, 0, stream>>>(X, Wq, Wk, Wv, bq, bk, bv,
                                     Xb, Wall, ball, rsum);

    // 2. fused QKV projection: legacy (1536 blocks = 2 rounds @3/CU, 741 TF)
    dim3 g1(3 * H_ / 128, (B_ * S_) / 128, 1);
    gemm_bt<128, 1, true, true, true, false, false><<<g1, 256, 0, stream>>>(
        Xb, H_, 0, Wall, H_, 0, ball, qk, 2 * H_, 0, vtb, nullptr,
        B_ * S_, 3 * H_, H_, 1.0f);

    // 3. exp-scores: 8-phase 256² (8x8x4 = 256 blocks = 1 round @1/CU)
    dim3 g2(S_ / 256, S_ / 256, B_);
    gemm8p<true, false, true><<<g2, 512, 0, stream>>>(
        qk,      2 * H_, (long long)S_ * 2 * H_,
        qk + H_, 2 * H_, (long long)S_ * 2 * H_,
        sc, S_, (long long)S_ * S_, rsum, H_, 0.03125f);

    // 4. out = (exp-scores @ vtb^T) / rsum: 8-phase 256² (4x8x4 = 128 blocks)
    dim3 g3(H_ / 256, S_ / 256, B_);
    gemm8p<false, true, false><<<g3, 512, 0, stream>>>(
        sc,  S_, (long long)S_ * S_,
        vtb, S_, (long long)H_ * S_,
        out, H_, (long long)S_ * H_, rsum, S_, 1.0f);
}